// Round 9
// baseline (305.372 us; speedup 1.0000x reference)
//
#include <hip/hip_runtime.h>
#include <stdint.h>

#define THRESH 1.5f
constexpr int NPIX  = 8 * 1024 * 1024;   // 2^23 pixels
constexpr int HW    = 1024 * 1024;       // pixels per image
constexpr int WW    = 1024;              // image width
constexpr int NWORD = NPIX / 32;         // 262144 mask words
constexpr int WPR   = WW / 32;           // 32 words per image row

constexpr int BLK     = 256;
constexpr int GRD_PX4 = NPIX / (BLK * 4);  // 8192 blocks (1024 px = ONE image row each)
constexpr int GRD_W   = NWORD / BLK;       // 1024 blocks (1 word/thread)

// Deterministic claim slots (round-2 lesson: per-block LDS ranks, never a hot
// global counter). Region = one row; E[claims/row] ~ 44-68; 128 = huge margin.
constexpr int SPB_R      = 128;
constexpr int BASE_SLOTS = GRD_PX4 * SPB_R;   // 1048576
constexpr int OVF_SLOTS  = 16384;
constexpr int CAP        = BASE_SLOTS + OVF_SLOTS;  // 1064960
constexpr int ZINT4 = CAP * 12 / 16;          // cnt+best zero region in int4s
static_assert((CAP * 12) % 16 == 0, "zero region must be int4-divisible");
static_assert(ZINT4 <= GRD_PX4 * BLK, "mask_init must cover the zero region");

constexpr int WLSTRIDE = 1024;             // worklist entries per row region

// ---------------------------------------------------------------------------
// parent[] encoding: < NPIX = union-find pointer (self <=> unclaimed root);
//                   >= NPIX = claimed root, compact id = value - NPIX.
// Links always point larger -> smaller index (monotone; no cycles).
// ---------------------------------------------------------------------------

// Path-halving find (union phase only — no claims exist yet, all values
// < NPIX). The halving store is a benign race: it always writes an ancestor.
__device__ __forceinline__ int find_root(int* __restrict__ P, int x) {
    int p = P[x];
    while (p != x) {
        int g = P[p];
        if (g != p) P[x] = g;   // halve
        x = p; p = g;
    }
    return x;
}

__device__ __forceinline__ void merge(int* P, int a, int b) {
    int ra = find_root(P, a);
    int rb = find_root(P, b);
    while (ra != rb) {
        if (ra < rb) { int t = ra; ra = rb; rb = t; }   // ra > rb
        int old = atomicCAS(&P[ra], ra, rb);            // link larger -> smaller
        if (old == ra) break;
        ra = find_root(P, old);
        rb = find_root(P, rb);
    }
}

// Pass 1: one block per image row. Read x once (float4), build fg bitmask,
// bulk-zero cnt/best, append (pixel, value_bits) worklist entries, and init
// parent with HORIZONTAL RUN STARTS (W-edges resolved here for free;
// union_k then only handles N/NW/NE).  [R4 verbatim]
__global__ void mask_init_k(const float* __restrict__ x, int* __restrict__ parent,
                            unsigned* __restrict__ mask, uint2* __restrict__ wl,
                            int* __restrict__ wl_cnt, int4* __restrict__ zbase,
                            int* __restrict__ ovf) {
    __shared__ unsigned s_nib[BLK];
    __shared__ unsigned s_word[WPR];
    __shared__ int s_rank;
    int t  = threadIdx.x;
    int gt = blockIdx.x * BLK + t;
    if (gt < ZINT4) zbase[gt] = make_int4(0, 0, 0, 0);
    int i4 = gt * 4;
    float4 v = *(const float4*)(x + i4);
    unsigned nib = (unsigned)(v.x >= THRESH) | ((unsigned)(v.y >= THRESH) << 1) |
                   ((unsigned)(v.z >= THRESH) << 2) | ((unsigned)(v.w >= THRESH) << 3);
    if (t == 0) s_rank = 0;
    s_nib[t] = nib;
    __syncthreads();
    if ((t & 7) == 0) {
        unsigned w = 0;
        #pragma unroll
        for (int k = 0; k < 8; k++) w |= s_nib[t + k] << (4 * k);
        s_word[t >> 3] = w;
        mask[gt >> 3] = w;
    }
    __syncthreads();

    // horizontal run starts for this thread's 4 pixels (row-relative indices)
    if (nib) {
        int rowstart = blockIdx.x << 10;     // global pixel index of row start
        int r0 = t << 2;                     // row-relative index of pixel 0
        int rs0 = 0, rs1 = 0, rs2 = 0, rs3 = 0;
        if (nib & 1u) {
            bool prevSet = (r0 != 0) &&
                ((s_word[(r0 - 1) >> 5] >> ((r0 - 1) & 31)) & 1u);
            if (!prevSet) rs0 = r0;
            else {
                int wI = r0 >> 5, b = r0 & 31;
                unsigned notset = b ? (~s_word[wI] & ((1u << b) - 1)) : 0u;
                int j = wI;
                if (!notset) {
                    j = wI - 1;
                    while (j >= 0 && s_word[j] == 0xFFFFFFFFu) j--;
                    notset = (j >= 0) ? ~s_word[j] : 0u;
                }
                rs0 = (j < 0) ? 0 : (j * 32 + (31 - __clz(notset)) + 1);
            }
        }
        if (nib & 2u) rs1 = (nib & 1u) ? rs0 : r0 + 1;
        if (nib & 4u) rs2 = (nib & 2u) ? rs1 : r0 + 2;
        if (nib & 8u) rs3 = (nib & 4u) ? rs2 : r0 + 3;
        int4 pv;
        pv.x = (nib & 1u) ? rowstart + rs0 : i4;
        pv.y = (nib & 2u) ? rowstart + rs1 : i4 + 1;
        pv.z = (nib & 4u) ? rowstart + rs2 : i4 + 2;
        pv.w = (nib & 8u) ? rowstart + rs3 : i4 + 3;
        *(int4*)(parent + i4) = pv;

        int nfg = __popc(nib);
        int r = atomicAdd(&s_rank, nfg);                // LDS atomic
        uint2* dst = wl + (size_t)blockIdx.x * WLSTRIDE;
        if (nib & 1u) dst[r++] = make_uint2((unsigned)i4,     __float_as_uint(v.x));
        if (nib & 2u) dst[r++] = make_uint2((unsigned)i4 + 1, __float_as_uint(v.y));
        if (nib & 4u) dst[r++] = make_uint2((unsigned)i4 + 2, __float_as_uint(v.z));
        if (nib & 8u) dst[r++] = make_uint2((unsigned)i4 + 3, __float_as_uint(v.w));
    }
    __syncthreads();
    if (t == 0) wl_cnt[blockIdx.x] = s_rank;
    if (gt == 0) *ovf = 0;
}

// Pass 2: per-WORD union, N-family only (W-edges pre-resolved by run-start
// parents). Merge thinning (bit-safe).  [R4 verbatim]
__global__ void union_k(const unsigned* __restrict__ mask, int* __restrict__ parent) {
    int w = blockIdx.x * BLK + threadIdx.x;
    int r = (w >> 5) & (WW - 1);    // row within image (words never cross rows)
    if (r == 0) return;             // image top row: no north neighbors
    unsigned cur = mask[w];
    if (!cur) return;
    int cw = w & (WPR - 1);         // word-column within row
    unsigned above     = mask[w - WPR];
    unsigned abovePrev = (cw > 0)       ? mask[w - WPR - 1] : 0u;
    unsigned aboveNext = (cw < WPR - 1) ? mask[w - WPR + 1] : 0u;
    unsigned mN  = cur & above;
    unsigned mNW = cur & ((above << 1) | (abovePrev >> 31));
    unsigned mNE = cur & ((above >> 1) | ((aboveNext & 1u) << 31));
    mNW &= ~mN;
    mNE &= ~mN;
    mN  &= ~(mN << 1);
    if (!(mN | mNW | mNE)) return;
    int base = w << 5;
    while (mN)  { int b = __ffs(mN)  - 1; mN  &= mN  - 1; merge(parent, base + b, base + b - WW); }
    while (mNW) { int b = __ffs(mNW) - 1; mNW &= mNW - 1; merge(parent, base + b, base + b - WW - 1); }
    while (mNE) { int b = __ffs(mNE) - 1; mNE &= mNE - 1; merge(parent, base + b, base + b - WW + 1); }
}

// Pass 3 (fused claim+stats): R4 verbatim, PLUS a calibrated ~59 us
// whole-workspace streaming read appended as DIAGNOSTIC PADDING (round 9):
// pushes cstats above the ~62 us fill dispatches so rocprof's top-5 finally
// shows its true duration and counters. dur(visible) - 59 ~ true cstats;
// FETCH(visible) - 393216 KB ~ true fetch. Remove next round.
__global__ void cstats_k(const uint2* __restrict__ wl, const int* __restrict__ wl_cnt,
                         int* __restrict__ parent, int* __restrict__ cnt,
                         unsigned long long* __restrict__ best,
                         int* __restrict__ ovf,
                         const float4* __restrict__ wsbase, int n4,
                         float* __restrict__ sink) {
    __shared__ int s_cnt;
    if (threadIdx.x == 0) s_cnt = 0;
    __syncthreads();
    int region = blockIdx.x;
    int c = wl_cnt[region];
    const uint2* src = wl + (size_t)region * WLSTRIDE;
    for (int j = threadIdx.x; j < c; j += 64) {
        uint2 e = src[j];
        int p = (int)e.x;
        int cid;
        int xn = p;
        while (true) {
            int pe = parent[xn];
            if (pe >= NPIX) { cid = pe - NPIX; break; }      // claimed terminal
            if (pe == xn) {                                  // unclaimed self-root
                int rank = atomicAdd(&s_cnt, 1);             // LDS atomic
                int slot;
                if (rank < SPB_R) slot = region * SPB_R + rank;
                else { int o2 = atomicAdd(ovf, 1);
                       slot = BASE_SLOTS + (o2 < OVF_SLOTS ? o2 : OVF_SLOTS - 1); }
                int old = atomicCAS(&parent[xn], xn, NPIX + slot);
                if (old == xn)    { cid = slot; break; }     // we claimed it
                if (old >= NPIX)  { cid = old - NPIX; break; } // lost the race
                xn = old;                                    // defensive
            } else {
                xn = pe;
            }
        }
        parent[p] = NPIX + cid;                 // full flatten for out_k
        atomicAdd(&cnt[cid], 1);
        unsigned within = (unsigned)(p & (HW - 1));
        unsigned long long pk =
            ((unsigned long long)e.y << 32) | (unsigned long long)(~within);
        atomicMax(&best[cid], pk);
    }
    // ---- diagnostic padding: grid-stride float4 sweep of the whole ws ----
    float s = 0.f;
    int tid = blockIdx.x * 64 + threadIdx.x;
    for (int i = tid; i < n4; i += GRD_PX4 * 64) {
        float4 pv = wsbase[i];
        s += pv.x + pv.y + pv.z + pv.w;
    }
    if (s == 1.2345678e30f) *sink = s;   // data-dependent, never fires; keeps loads
}

// Pass 4: emit float32 planes (max,row,col) with float4 stores. [R4 verbatim]
__device__ __forceinline__ void lookup_one(const int* __restrict__ parent,
                                           const int* __restrict__ cnt,
                                           const unsigned long long* __restrict__ best,
                                           int p, float& om, float& orow, float& ocol) {
    int cid = parent[p] - NPIX;
    if (cid >= 0 && cid < CAP && cnt[cid] > 3) {       // area > MIN_AREA
        unsigned long long pk = best[cid];
        om   = __uint_as_float((unsigned)(pk >> 32));
        unsigned idx = ~((unsigned)pk);                // within-image flat idx
        orow = (float)(idx >> 10);
        ocol = (float)(idx & (WW - 1));
    }
}

__global__ void out_k(const unsigned* __restrict__ mask, const int* __restrict__ parent,
                      const int* __restrict__ cnt,
                      const unsigned long long* __restrict__ best,
                      float* __restrict__ o) {
    int t = blockIdx.x * BLK + threadIdx.x;
    unsigned nib = (mask[t >> 3] >> ((t & 7) * 4)) & 0xFu;
    int i4 = t * 4;
    float4 m  = make_float4(0.f, 0.f, 0.f, 0.f);
    float4 rr = make_float4(-1.f, -1.f, -1.f, -1.f);
    float4 cc = make_float4(-1.f, -1.f, -1.f, -1.f);
    if (nib) {
        if (nib & 1u) lookup_one(parent, cnt, best, i4,     m.x, rr.x, cc.x);
        if (nib & 2u) lookup_one(parent, cnt, best, i4 + 1, m.y, rr.y, cc.y);
        if (nib & 4u) lookup_one(parent, cnt, best, i4 + 2, m.z, rr.z, cc.z);
        if (nib & 8u) lookup_one(parent, cnt, best, i4 + 3, m.w, rr.w, cc.w);
    }
    *(float4*)(o + i4)            = m;
    *(float4*)(o + NPIX + i4)     = rr;
    *(float4*)(o + 2 * NPIX + i4) = cc;
}

// ---------------------------------------------------------------------------
extern "C" void kernel_launch(void* const* d_in, const int* in_sizes, int n_in,
                              void* d_out, int out_size, void* d_ws, size_t ws_size,
                              hipStream_t stream) {
    const float* x = (const float*)d_in[0];
    float* o = (float*)d_out;

    // ws layout: parent i32[NPIX] 33.5MB | best u64[CAP] 8.5MB | cnt i32[CAP]
    // 4.3MB | mask u32[NWORD] 1MB | wl_cnt i32[8192] | wl uint2[8192*1024]
    // 67MB | ovf | sink. Total ~115MB (< 384MB ws).
    char* base = (char*)d_ws;
    int* parent = (int*)base;
    size_t off = (size_t)NPIX * 4;
    unsigned long long* best = (unsigned long long*)(base + off);
    int4* zbase = (int4*)(base + off);                             off += (size_t)CAP * 8;
    int* cnt       = (int*)(base + off);                           off += (size_t)CAP * 4;
    unsigned* mask = (unsigned*)(base + off);                      off += (size_t)NWORD * 4;
    int* wl_cnt    = (int*)(base + off);                           off += (size_t)GRD_PX4 * 4;
    uint2* wl      = (uint2*)(base + off);                         off += (size_t)GRD_PX4 * WLSTRIDE * 8;
    int* ovf       = (int*)(base + off);                           off += 64;
    float* sink    = (float*)(base + off);

    int n4 = (int)(ws_size / 16);   // whole-ws float4 count for the pad sweep

    mask_init_k<<<GRD_PX4, BLK, 0, stream>>>(x, parent, mask, wl, wl_cnt, zbase, ovf);
    union_k    <<<GRD_W,   BLK, 0, stream>>>(mask, parent);
    cstats_k   <<<GRD_PX4, 64,  0, stream>>>(wl, wl_cnt, parent, cnt, best, ovf,
                                             (const float4*)d_ws, n4, sink);
    out_k      <<<GRD_PX4, BLK, 0, stream>>>(mask, parent, cnt, best, o);
}

// Round 10
// 196.220 us; speedup vs baseline: 1.5563x; 1.5563x over previous
//
#include <hip/hip_runtime.h>
#include <stdint.h>

#define THRESH 1.5f
constexpr int NPIX  = 8 * 1024 * 1024;   // 2^23 pixels
constexpr int HW    = 1024 * 1024;       // pixels per image
constexpr int WW    = 1024;              // image width
constexpr int NWORD = NPIX / 32;         // 262144 mask words
constexpr int WPR   = WW / 32;           // 32 words per image row

constexpr int BLK     = 256;
constexpr int GRD_PX4 = NPIX / (BLK * 4);  // 8192 blocks (1024 px = ONE image row each)
constexpr int GRD_W   = NWORD / BLK;       // 1024 blocks (1 word/thread)

// Deterministic claim slots (round-2 lesson: per-block LDS ranks, never a hot
// global counter). Region = one row; E[claims/row] ~ 44-68; 128 = huge margin.
constexpr int SPB_R      = 128;
constexpr int BASE_SLOTS = GRD_PX4 * SPB_R;   // 1048576
constexpr int OVF_SLOTS  = 16384;
constexpr int CAP        = BASE_SLOTS + OVF_SLOTS;  // 1064960
constexpr int ZINT4 = CAP * 12 / 16;          // cnt+best zero region in int4s
static_assert((CAP * 12) % 16 == 0, "zero region must be int4-divisible");
static_assert(ZINT4 <= GRD_PX4 * BLK, "mask_init must cover the zero region");

constexpr int WLSTRIDE = 1024;             // worklist entries per row region

// ---------------------------------------------------------------------------
// parent[] encoding: < NPIX = union-find pointer (self <=> unclaimed root);
//                   >= NPIX = claimed root, compact id = value - NPIX.
// Links always point larger -> smaller index (monotone; no cycles).
// ---------------------------------------------------------------------------

// Path-halving find (union phase only — no claims exist yet, all values
// < NPIX). The halving store is a benign race: it always writes an ancestor.
__device__ __forceinline__ int find_root(int* __restrict__ P, int x) {
    int p = P[x];
    while (p != x) {
        int g = P[p];
        if (g != p) P[x] = g;   // halve
        x = p; p = g;
    }
    return x;
}

__device__ __forceinline__ void merge(int* P, int a, int b) {
    int ra = find_root(P, a);
    int rb = find_root(P, b);
    while (ra != rb) {
        if (ra < rb) { int t = ra; ra = rb; rb = t; }   // ra > rb
        int old = atomicCAS(&P[ra], ra, rb);            // link larger -> smaller
        if (old == ra) break;
        ra = find_root(P, old);
        rb = find_root(P, rb);
    }
}

// Pass 1: one block per image row. Read x once (float4), build fg bitmask,
// bulk-zero cnt/best, append (pixel, value_bits) worklist entries, and init
// parent with HORIZONTAL RUN STARTS (W-edges resolved here for free;
// union_k then only handles N/NW/NE).
__global__ void mask_init_k(const float* __restrict__ x, int* __restrict__ parent,
                            unsigned* __restrict__ mask, uint2* __restrict__ wl,
                            int* __restrict__ wl_cnt, int4* __restrict__ zbase,
                            int* __restrict__ ovf) {
    __shared__ unsigned s_nib[BLK];
    __shared__ unsigned s_word[WPR];
    __shared__ int s_rank;
    int t  = threadIdx.x;
    int gt = blockIdx.x * BLK + t;
    if (gt < ZINT4) zbase[gt] = make_int4(0, 0, 0, 0);
    int i4 = gt * 4;
    float4 v = *(const float4*)(x + i4);
    unsigned nib = (unsigned)(v.x >= THRESH) | ((unsigned)(v.y >= THRESH) << 1) |
                   ((unsigned)(v.z >= THRESH) << 2) | ((unsigned)(v.w >= THRESH) << 3);
    if (t == 0) s_rank = 0;
    s_nib[t] = nib;
    __syncthreads();
    if ((t & 7) == 0) {
        unsigned w = 0;
        #pragma unroll
        for (int k = 0; k < 8; k++) w |= s_nib[t + k] << (4 * k);
        s_word[t >> 3] = w;
        mask[gt >> 3] = w;
    }
    __syncthreads();

    // horizontal run starts for this thread's 4 pixels (row-relative indices)
    if (nib) {
        int rowstart = blockIdx.x << 10;     // global pixel index of row start
        int r0 = t << 2;                     // row-relative index of pixel 0
        int rs0 = 0, rs1 = 0, rs2 = 0, rs3 = 0;
        if (nib & 1u) {
            bool prevSet = (r0 != 0) &&
                ((s_word[(r0 - 1) >> 5] >> ((r0 - 1) & 31)) & 1u);
            if (!prevSet) rs0 = r0;
            else {
                int wI = r0 >> 5, b = r0 & 31;
                unsigned notset = b ? (~s_word[wI] & ((1u << b) - 1)) : 0u;
                int j = wI;
                if (!notset) {
                    j = wI - 1;
                    while (j >= 0 && s_word[j] == 0xFFFFFFFFu) j--;
                    notset = (j >= 0) ? ~s_word[j] : 0u;
                }
                rs0 = (j < 0) ? 0 : (j * 32 + (31 - __clz(notset)) + 1);
            }
        }
        if (nib & 2u) rs1 = (nib & 1u) ? rs0 : r0 + 1;
        if (nib & 4u) rs2 = (nib & 2u) ? rs1 : r0 + 2;
        if (nib & 8u) rs3 = (nib & 4u) ? rs2 : r0 + 3;
        int4 pv;
        pv.x = (nib & 1u) ? rowstart + rs0 : i4;
        pv.y = (nib & 2u) ? rowstart + rs1 : i4 + 1;
        pv.z = (nib & 4u) ? rowstart + rs2 : i4 + 2;
        pv.w = (nib & 8u) ? rowstart + rs3 : i4 + 3;
        *(int4*)(parent + i4) = pv;

        int nfg = __popc(nib);
        int r = atomicAdd(&s_rank, nfg);                // LDS atomic
        uint2* dst = wl + (size_t)blockIdx.x * WLSTRIDE;
        if (nib & 1u) dst[r++] = make_uint2((unsigned)i4,     __float_as_uint(v.x));
        if (nib & 2u) dst[r++] = make_uint2((unsigned)i4 + 1, __float_as_uint(v.y));
        if (nib & 4u) dst[r++] = make_uint2((unsigned)i4 + 2, __float_as_uint(v.z));
        if (nib & 8u) dst[r++] = make_uint2((unsigned)i4 + 3, __float_as_uint(v.w));
    }
    __syncthreads();
    if (t == 0) wl_cnt[blockIdx.x] = s_rank;
    if (gt == 0) *ovf = 0;
}

// Pass 2: per-WORD union, N-family only (W-edges pre-resolved by run-start
// parents). Merge thinning (bit-safe): mNW/mNE redundant when the pixel also
// N-connects (above bits W-adjacent = same above-run); consecutive N-contacts
// within one run/above-run pair need only the first.
__global__ void union_k(const unsigned* __restrict__ mask, int* __restrict__ parent) {
    int w = blockIdx.x * BLK + threadIdx.x;
    int r = (w >> 5) & (WW - 1);    // row within image (words never cross rows)
    if (r == 0) return;             // image top row: no north neighbors
    unsigned cur = mask[w];
    if (!cur) return;
    int cw = w & (WPR - 1);         // word-column within row
    unsigned above     = mask[w - WPR];
    unsigned abovePrev = (cw > 0)       ? mask[w - WPR - 1] : 0u;
    unsigned aboveNext = (cw < WPR - 1) ? mask[w - WPR + 1] : 0u;
    unsigned mN  = cur & above;
    unsigned mNW = cur & ((above << 1) | (abovePrev >> 31));
    unsigned mNE = cur & ((above >> 1) | ((aboveNext & 1u) << 31));
    mNW &= ~mN;
    mNE &= ~mN;
    mN  &= ~(mN << 1);
    if (!(mN | mNW | mNE)) return;
    int base = w << 5;
    while (mN)  { int b = __ffs(mN)  - 1; mN  &= mN  - 1; merge(parent, base + b, base + b - WW); }
    while (mNW) { int b = __ffs(mNW) - 1; mNW &= mNW - 1; merge(parent, base + b, base + b - WW - 1); }
    while (mNE) { int b = __ffs(mNE) - 1; mNE &= mNE - 1; merge(parent, base + b, base + b - WW + 1); }
}

// Pass 3 (fused claim+stats): one wave per row region over the worklist.
// Claims roots on the fly with deterministic per-block slots (LDS rank +
// region*SPB_R base), fully flattens parent[p] -> NPIX+cid (out_k invariant:
// every fg pixel is its own wl entry, flattened exactly once; values >= NPIX
// never decrease — hence NO path-halving stores in this walk), and
// accumulates area + fused (max value, min index of max) via one 64-bit
// atomicMax on (float_bits << 32) | ~within_index.
__global__ void cstats_k(const uint2* __restrict__ wl, const int* __restrict__ wl_cnt,
                         int* __restrict__ parent, int* __restrict__ cnt,
                         unsigned long long* __restrict__ best,
                         int* __restrict__ ovf) {
    __shared__ int s_cnt;
    if (threadIdx.x == 0) s_cnt = 0;
    __syncthreads();
    int region = blockIdx.x;
    int c = wl_cnt[region];
    const uint2* src = wl + (size_t)region * WLSTRIDE;
    for (int j = threadIdx.x; j < c; j += 64) {
        uint2 e = src[j];
        int p = (int)e.x;
        int cid;
        int xn = p;
        while (true) {
            int pe = parent[xn];
            if (pe >= NPIX) { cid = pe - NPIX; break; }      // claimed terminal
            if (pe == xn) {                                  // unclaimed self-root
                int rank = atomicAdd(&s_cnt, 1);             // LDS atomic
                int slot;
                if (rank < SPB_R) slot = region * SPB_R + rank;
                else { int o2 = atomicAdd(ovf, 1);
                       slot = BASE_SLOTS + (o2 < OVF_SLOTS ? o2 : OVF_SLOTS - 1); }
                int old = atomicCAS(&parent[xn], xn, NPIX + slot);
                if (old == xn)    { cid = slot; break; }     // we claimed it
                if (old >= NPIX)  { cid = old - NPIX; break; } // lost the race
                xn = old;                                    // defensive
            } else {
                xn = pe;
            }
        }
        parent[p] = NPIX + cid;                 // full flatten for out_k
        atomicAdd(&cnt[cid], 1);
        unsigned within = (unsigned)(p & (HW - 1));
        unsigned long long pk =
            ((unsigned long long)e.y << 32) | (unsigned long long)(~within);
        atomicMax(&best[cid], pk);
    }
}

// Pass 4: emit float32 planes (max,row,col) with float4 stores.
// parent[p] is fully flattened for every fg pixel: one read -> cid.
__device__ __forceinline__ void lookup_one(const int* __restrict__ parent,
                                           const int* __restrict__ cnt,
                                           const unsigned long long* __restrict__ best,
                                           int p, float& om, float& orow, float& ocol) {
    int cid = parent[p] - NPIX;
    if (cid >= 0 && cid < CAP && cnt[cid] > 3) {       // area > MIN_AREA
        unsigned long long pk = best[cid];
        om   = __uint_as_float((unsigned)(pk >> 32));
        unsigned idx = ~((unsigned)pk);                // within-image flat idx
        orow = (float)(idx >> 10);
        ocol = (float)(idx & (WW - 1));
    }
}

__global__ void out_k(const unsigned* __restrict__ mask, const int* __restrict__ parent,
                      const int* __restrict__ cnt,
                      const unsigned long long* __restrict__ best,
                      float* __restrict__ o) {
    int t = blockIdx.x * BLK + threadIdx.x;
    unsigned nib = (mask[t >> 3] >> ((t & 7) * 4)) & 0xFu;
    int i4 = t * 4;
    float4 m  = make_float4(0.f, 0.f, 0.f, 0.f);
    float4 rr = make_float4(-1.f, -1.f, -1.f, -1.f);
    float4 cc = make_float4(-1.f, -1.f, -1.f, -1.f);
    if (nib) {
        if (nib & 1u) lookup_one(parent, cnt, best, i4,     m.x, rr.x, cc.x);
        if (nib & 2u) lookup_one(parent, cnt, best, i4 + 1, m.y, rr.y, cc.y);
        if (nib & 4u) lookup_one(parent, cnt, best, i4 + 2, m.z, rr.z, cc.z);
        if (nib & 8u) lookup_one(parent, cnt, best, i4 + 3, m.w, rr.w, cc.w);
    }
    *(float4*)(o + i4)            = m;
    *(float4*)(o + NPIX + i4)     = rr;
    *(float4*)(o + 2 * NPIX + i4) = cc;
}

// ---------------------------------------------------------------------------
extern "C" void kernel_launch(void* const* d_in, const int* in_sizes, int n_in,
                              void* d_out, int out_size, void* d_ws, size_t ws_size,
                              hipStream_t stream) {
    const float* x = (const float*)d_in[0];
    float* o = (float*)d_out;

    // ws layout: parent i32[NPIX] 33.5MB | best u64[CAP] 8.5MB | cnt i32[CAP]
    // 4.3MB | mask u32[NWORD] 1MB | wl_cnt i32[8192] | wl uint2[8192*1024]
    // 67MB | ovf. Total ~115MB (< 384MB ws).
    char* base = (char*)d_ws;
    int* parent = (int*)base;
    size_t off = (size_t)NPIX * 4;
    unsigned long long* best = (unsigned long long*)(base + off);
    int4* zbase = (int4*)(base + off);                             off += (size_t)CAP * 8;
    int* cnt       = (int*)(base + off);                           off += (size_t)CAP * 4;
    unsigned* mask = (unsigned*)(base + off);                      off += (size_t)NWORD * 4;
    int* wl_cnt    = (int*)(base + off);                           off += (size_t)GRD_PX4 * 4;
    uint2* wl      = (uint2*)(base + off);                         off += (size_t)GRD_PX4 * WLSTRIDE * 8;
    int* ovf       = (int*)(base + off);

    mask_init_k<<<GRD_PX4, BLK, 0, stream>>>(x, parent, mask, wl, wl_cnt, zbase, ovf);
    union_k    <<<GRD_W,   BLK, 0, stream>>>(mask, parent);
    cstats_k   <<<GRD_PX4, 64,  0, stream>>>(wl, wl_cnt, parent, cnt, best, ovf);
    out_k      <<<GRD_PX4, BLK, 0, stream>>>(mask, parent, cnt, best, o);
}